// Round 2
// baseline (269.775 us; speedup 1.0000x reference)
//
#include <hip/hip_runtime.h>
#include <hip/hip_cooperative_groups.h>

namespace cg = cooperative_groups;

// Fused single-launch version:
//   Phase 1: tab[n] = (dot(h[n],W[0][:128]), dot(h[n],W[1][:128]),
//                      dot(h[n],W[0][128:]), dot(h[n],W[1][128:]))
//   grid.sync()
//   Phase 2: out[e] = (tab[src].x + tab[dst].z + b0, tab[src].y + tab[dst].w + b1)
// 4 threads per node in phase 1; tables are 800 KB -> L2-resident for phase 2.
__global__ __launch_bounds__(256, 4) void fused_edge_mlp_kernel(
    const float* __restrict__ h, const int* __restrict__ src,
    const int* __restrict__ dst, const float* __restrict__ W,
    const float* __restrict__ bias, float4* __restrict__ tab,
    float2* __restrict__ out, int n_nodes, int n_edges) {
  __shared__ float sW[512];  // W [2][256] = 2 KB
  const int tid = threadIdx.x;
  if (tid < 128) {
    reinterpret_cast<float4*>(sW)[tid] = reinterpret_cast<const float4*>(W)[tid];
  }
  __syncthreads();

  // ---- Phase 1: node dot tables (4 threads/node, grid-stride) ----
  const int quad = tid & 3;
  const int nodes_per_blk = 64;  // 256 threads / 4
  for (int node = blockIdx.x * nodes_per_blk + (tid >> 2); node < n_nodes;
       node += gridDim.x * nodes_per_blk) {
    const float* hrow = h + (size_t)node * 128;
    float a0 = 0.f, a1 = 0.f, b0 = 0.f, b1 = 0.f;
#pragma unroll
    for (int k = 0; k < 8; ++k) {
      const int d = quad * 4 + k * 16;
      const float4 hv = *reinterpret_cast<const float4*>(hrow + d);
      const float4 w0 = *reinterpret_cast<const float4*>(sW + d);        // W[0][0:128]
      const float4 w1 = *reinterpret_cast<const float4*>(sW + 256 + d);  // W[1][0:128]
      const float4 w2 = *reinterpret_cast<const float4*>(sW + 128 + d);  // W[0][128:]
      const float4 w3 = *reinterpret_cast<const float4*>(sW + 384 + d);  // W[1][128:]
      a0 += hv.x * w0.x + hv.y * w0.y + hv.z * w0.z + hv.w * w0.w;
      a1 += hv.x * w1.x + hv.y * w1.y + hv.z * w1.z + hv.w * w1.w;
      b0 += hv.x * w2.x + hv.y * w2.y + hv.z * w2.z + hv.w * w2.w;
      b1 += hv.x * w3.x + hv.y * w3.y + hv.z * w3.z + hv.w * w3.w;
    }
    a0 += __shfl_xor(a0, 1); a0 += __shfl_xor(a0, 2);
    a1 += __shfl_xor(a1, 1); a1 += __shfl_xor(a1, 2);
    b0 += __shfl_xor(b0, 1); b0 += __shfl_xor(b0, 2);
    b1 += __shfl_xor(b1, 1); b1 += __shfl_xor(b1, 2);
    if (quad == 0) tab[node] = make_float4(a0, a1, b0, b1);
  }

  __threadfence();        // make table visible device-wide (cross-XCD)
  cg::this_grid().sync();

  // ---- Phase 2: per-edge adds (grid-stride) ----
  const float bx = bias[0], by = bias[1];
  for (int e = blockIdx.x * blockDim.x + tid; e < n_edges;
       e += gridDim.x * blockDim.x) {
    const float4 a = tab[src[e]];
    const float4 b = tab[dst[e]];
    out[e] = make_float2(a.x + b.z + bx, a.y + b.w + by);
  }
}

// ---------------- Fallback two-kernel path ----------------
__global__ __launch_bounds__(256) void node_dots_kernel(
    const float* __restrict__ h, const float* __restrict__ W,
    float4* __restrict__ tab, int n_nodes) {
  __shared__ float sW[512];
  const int tid = threadIdx.x;
  if (tid < 128) {
    reinterpret_cast<float4*>(sW)[tid] = reinterpret_cast<const float4*>(W)[tid];
  }
  __syncthreads();
  const int node = blockIdx.x * 64 + (tid >> 2);
  if (node >= n_nodes) return;
  const int quad = tid & 3;
  const float* hrow = h + (size_t)node * 128;
  float a0 = 0.f, a1 = 0.f, b0 = 0.f, b1 = 0.f;
#pragma unroll
  for (int k = 0; k < 8; ++k) {
    const int d = quad * 4 + k * 16;
    const float4 hv = *reinterpret_cast<const float4*>(hrow + d);
    const float4 w0 = *reinterpret_cast<const float4*>(sW + d);
    const float4 w1 = *reinterpret_cast<const float4*>(sW + 256 + d);
    const float4 w2 = *reinterpret_cast<const float4*>(sW + 128 + d);
    const float4 w3 = *reinterpret_cast<const float4*>(sW + 384 + d);
    a0 += hv.x * w0.x + hv.y * w0.y + hv.z * w0.z + hv.w * w0.w;
    a1 += hv.x * w1.x + hv.y * w1.y + hv.z * w1.z + hv.w * w1.w;
    b0 += hv.x * w2.x + hv.y * w2.y + hv.z * w2.z + hv.w * w2.w;
    b1 += hv.x * w3.x + hv.y * w3.y + hv.z * w3.z + hv.w * w3.w;
  }
  a0 += __shfl_xor(a0, 1); a0 += __shfl_xor(a0, 2);
  a1 += __shfl_xor(a1, 1); a1 += __shfl_xor(a1, 2);
  b0 += __shfl_xor(b0, 1); b0 += __shfl_xor(b0, 2);
  b1 += __shfl_xor(b1, 1); b1 += __shfl_xor(b1, 2);
  if (quad == 0) tab[node] = make_float4(a0, a1, b0, b1);
}

__global__ __launch_bounds__(256) void edge_scores_kernel(
    const int* __restrict__ src, const int* __restrict__ dst,
    const float4* __restrict__ tab, const float* __restrict__ bias,
    float2* __restrict__ out, int n_edges) {
  const int e = blockIdx.x * blockDim.x + threadIdx.x;
  if (e >= n_edges) return;
  const float4 a = tab[src[e]];
  const float4 b = tab[dst[e]];
  out[e] = make_float2(a.x + b.z + bias[0], a.y + b.w + bias[1]);
}

extern "C" void kernel_launch(void* const* d_in, const int* in_sizes, int n_in,
                              void* d_out, int out_size, void* d_ws, size_t ws_size,
                              hipStream_t stream) {
  const float* h    = (const float*)d_in[0];
  const int*   src  = (const int*)d_in[1];
  const int*   dst  = (const int*)d_in[2];
  const float* W    = (const float*)d_in[3];
  const float* bias = (const float*)d_in[4];
  float2* out = (float2*)d_out;

  int n_nodes = in_sizes[0] / 128;
  int n_edges = in_sizes[1];
  float4* tab = (float4*)d_ws;  // n_nodes * 16 B

  bool coop_ok = false;
  if (ws_size >= (size_t)n_nodes * sizeof(float4)) {
    dim3 grid(1024), block(256);
    void* args[] = {(void*)&h, (void*)&src, (void*)&dst, (void*)&W,
                    (void*)&bias, (void*)&tab, (void*)&out,
                    (void*)&n_nodes, (void*)&n_edges};
    hipError_t err = hipLaunchCooperativeKernel(
        (const void*)fused_edge_mlp_kernel, grid, block, args, 0, stream);
    coop_ok = (err == hipSuccess);
  }
  if (!coop_ok && ws_size >= (size_t)n_nodes * sizeof(float4)) {
    node_dots_kernel<<<(n_nodes + 63) / 64, 256, 0, stream>>>(h, W, tab, n_nodes);
    edge_scores_kernel<<<(n_edges + 255) / 256, 256, 0, stream>>>(
        src, dst, tab, bias, out, n_edges);
  }
}

// Round 4
// 234.155 us; speedup vs baseline: 1.1521x; 1.1521x over previous
//
#include <hip/hip_runtime.h>

// Fused single-dispatch version with a hand-rolled grid barrier.
//   Phase 1: tab[n] = (dot(h[n],W[0][:128]), dot(h[n],W[1][:128]),
//                      dot(h[n],W[0][128:]), dot(h[n],W[1][128:]))
//   grid barrier (counter in d_ws, reset by hipMemsetAsync each launch)
//   Phase 2: out[e] = (tab[src].x + tab[dst].z + b0, tab[src].y + tab[dst].w + b1)
//
// Co-residency: 1024 blocks, __launch_bounds__(256,4) -> >=4 waves/EU ->
// >=4 blocks/CU x 256 CU = 1024 resident blocks. All blocks reach the
// barrier; no deadlock.
__global__ __launch_bounds__(256, 4) void fused_edge_mlp_kernel(
    const float* __restrict__ h, const int* __restrict__ src,
    const int* __restrict__ dst, const float* __restrict__ W,
    const float* __restrict__ bias, float4* __restrict__ tab,
    unsigned* __restrict__ ctr, float2* __restrict__ out,
    int n_nodes, int n_edges) {
  __shared__ float sW[512];  // W [2][256] = 2 KB
  const int tid = threadIdx.x;
  if (tid < 128) {
    reinterpret_cast<float4*>(sW)[tid] = reinterpret_cast<const float4*>(W)[tid];
  }
  __syncthreads();

  // ---- Phase 1: node dot tables (4 threads/node) ----
  const int quad = tid & 3;
  for (int node = blockIdx.x * 64 + (tid >> 2); node < n_nodes;
       node += gridDim.x * 64) {
    const float* hrow = h + (size_t)node * 128;
    float a0 = 0.f, a1 = 0.f, b0 = 0.f, b1 = 0.f;
#pragma unroll
    for (int k = 0; k < 8; ++k) {
      const int d = quad * 4 + k * 16;
      const float4 hv = *reinterpret_cast<const float4*>(hrow + d);
      const float4 w0 = *reinterpret_cast<const float4*>(sW + d);        // W[0][0:128]
      const float4 w1 = *reinterpret_cast<const float4*>(sW + 256 + d);  // W[1][0:128]
      const float4 w2 = *reinterpret_cast<const float4*>(sW + 128 + d);  // W[0][128:]
      const float4 w3 = *reinterpret_cast<const float4*>(sW + 384 + d);  // W[1][128:]
      a0 += hv.x * w0.x + hv.y * w0.y + hv.z * w0.z + hv.w * w0.w;
      a1 += hv.x * w1.x + hv.y * w1.y + hv.z * w1.z + hv.w * w1.w;
      b0 += hv.x * w2.x + hv.y * w2.y + hv.z * w2.z + hv.w * w2.w;
      b1 += hv.x * w3.x + hv.y * w3.y + hv.z * w3.z + hv.w * w3.w;
    }
    a0 += __shfl_xor(a0, 1); a0 += __shfl_xor(a0, 2);
    a1 += __shfl_xor(a1, 1); a1 += __shfl_xor(a1, 2);
    b0 += __shfl_xor(b0, 1); b0 += __shfl_xor(b0, 2);
    b1 += __shfl_xor(b1, 1); b1 += __shfl_xor(b1, 2);
    if (quad == 0) tab[node] = make_float4(a0, a1, b0, b1);
  }

  // ---- Grid barrier ----
  __syncthreads();  // all waves in this block done with tab stores
  if (tid == 0) {
    __threadfence();  // RELEASE: flush this block's tab writes device-wide
    unsigned arrived = __hip_atomic_fetch_add(ctr, 1u, __ATOMIC_ACQ_REL,
                                              __HIP_MEMORY_SCOPE_AGENT) + 1;
    if (arrived < gridDim.x) {
      while (__hip_atomic_load(ctr, __ATOMIC_ACQUIRE,
                               __HIP_MEMORY_SCOPE_AGENT) < gridDim.x) {
        __builtin_amdgcn_s_sleep(7);
      }
    }
    __threadfence();  // ACQUIRE side: discard stale cached tab lines
  }
  __syncthreads();

  // ---- Phase 2: per-edge adds, 2 edges/thread ----
  const float bx = bias[0], by = bias[1];
  const int np = gridDim.x * blockDim.x;
  const int npairs = n_edges >> 1;
  for (int p = blockIdx.x * blockDim.x + tid; p < npairs; p += np) {
    const int2 s2 = reinterpret_cast<const int2*>(src)[p];
    const int2 d2 = reinterpret_cast<const int2*>(dst)[p];
    const float4 a0 = tab[s2.x];
    const float4 b0 = tab[d2.x];
    const float4 a1 = tab[s2.y];
    const float4 b1 = tab[d2.y];
    reinterpret_cast<float4*>(out)[p] =
        make_float4(a0.x + b0.z + bx, a0.y + b0.w + by,
                    a1.x + b1.z + bx, a1.y + b1.w + by);
  }
  // odd tail
  if (blockIdx.x == 0 && tid == 0 && (n_edges & 1)) {
    const int e = n_edges - 1;
    const float4 a = tab[src[e]];
    const float4 b = tab[dst[e]];
    out[e] = make_float2(a.x + b.z + bx, a.y + b.w + by);
  }
}

// ---------------- Fallback two-kernel path ----------------
__global__ __launch_bounds__(256) void node_dots_kernel(
    const float* __restrict__ h, const float* __restrict__ W,
    float4* __restrict__ tab, int n_nodes) {
  __shared__ float sW[512];
  const int tid = threadIdx.x;
  if (tid < 128) {
    reinterpret_cast<float4*>(sW)[tid] = reinterpret_cast<const float4*>(W)[tid];
  }
  __syncthreads();
  const int node = blockIdx.x * 64 + (tid >> 2);
  if (node >= n_nodes) return;
  const int quad = tid & 3;
  const float* hrow = h + (size_t)node * 128;
  float a0 = 0.f, a1 = 0.f, b0 = 0.f, b1 = 0.f;
#pragma unroll
  for (int k = 0; k < 8; ++k) {
    const int d = quad * 4 + k * 16;
    const float4 hv = *reinterpret_cast<const float4*>(hrow + d);
    const float4 w0 = *reinterpret_cast<const float4*>(sW + d);
    const float4 w1 = *reinterpret_cast<const float4*>(sW + 256 + d);
    const float4 w2 = *reinterpret_cast<const float4*>(sW + 128 + d);
    const float4 w3 = *reinterpret_cast<const float4*>(sW + 384 + d);
    a0 += hv.x * w0.x + hv.y * w0.y + hv.z * w0.z + hv.w * w0.w;
    a1 += hv.x * w1.x + hv.y * w1.y + hv.z * w1.z + hv.w * w1.w;
    b0 += hv.x * w2.x + hv.y * w2.y + hv.z * w2.z + hv.w * w2.w;
    b1 += hv.x * w3.x + hv.y * w3.y + hv.z * w3.z + hv.w * w3.w;
  }
  a0 += __shfl_xor(a0, 1); a0 += __shfl_xor(a0, 2);
  a1 += __shfl_xor(a1, 1); a1 += __shfl_xor(a1, 2);
  b0 += __shfl_xor(b0, 1); b0 += __shfl_xor(b0, 2);
  b1 += __shfl_xor(b1, 1); b1 += __shfl_xor(b1, 2);
  if (quad == 0) tab[node] = make_float4(a0, a1, b0, b1);
}

__global__ __launch_bounds__(256) void edge_scores_kernel(
    const int* __restrict__ src, const int* __restrict__ dst,
    const float4* __restrict__ tab, const float* __restrict__ bias,
    float2* __restrict__ out, int n_edges) {
  const int e = blockIdx.x * blockDim.x + threadIdx.x;
  if (e >= n_edges) return;
  const float4 a = tab[src[e]];
  const float4 b = tab[dst[e]];
  out[e] = make_float2(a.x + b.z + bias[0], a.y + b.w + bias[1]);
}

extern "C" void kernel_launch(void* const* d_in, const int* in_sizes, int n_in,
                              void* d_out, int out_size, void* d_ws, size_t ws_size,
                              hipStream_t stream) {
  const float* h    = (const float*)d_in[0];
  const int*   src  = (const int*)d_in[1];
  const int*   dst  = (const int*)d_in[2];
  const float* W    = (const float*)d_in[3];
  const float* bias = (const float*)d_in[4];
  float2* out = (float2*)d_out;

  const int n_nodes = in_sizes[0] / 128;
  const int n_edges = in_sizes[1];

  const size_t tab_bytes = (size_t)n_nodes * sizeof(float4);
  const size_t ctr_off = (tab_bytes + 255) & ~(size_t)255;
  float4* tab = (float4*)d_ws;

  if (ws_size >= ctr_off + sizeof(unsigned)) {
    unsigned* ctr = (unsigned*)((char*)d_ws + ctr_off);
    (void)hipMemsetAsync(ctr, 0, sizeof(unsigned), stream);
    fused_edge_mlp_kernel<<<1024, 256, 0, stream>>>(
        h, src, dst, W, bias, tab, ctr, out, n_nodes, n_edges);
  } else if (ws_size >= tab_bytes) {
    node_dots_kernel<<<(n_nodes + 63) / 64, 256, 0, stream>>>(h, W, tab, n_nodes);
    edge_scores_kernel<<<(n_edges + 255) / 256, 256, 0, stream>>>(
        src, dst, tab, bias, out, n_edges);
  }
}

// Round 6
// 17.011 us; speedup vs baseline: 15.8586x; 13.7647x over previous
//
#include <hip/hip_runtime.h>

// Two-kernel pipeline (grid barriers on MI355X cost ~250us in contended
// device-scope atomics — measured rounds 2/4 — so two launches win).
//
// Kernel 1: per-node partial dots, 4 threads/node:
//   tabA[n] = ( dot(h[n], W[0][0:128]),   dot(h[n], W[1][0:128])   )
//   tabB[n] = ( dot(h[n], W[0][128:256]), dot(h[n], W[1][128:256]) )
// Kernel 2: out[e] = tabA[src[e]] + tabB[dst[e]] + bias
//   tabA/tabB are 400 KB each -> L2-resident; 8 B gathers.

__global__ __launch_bounds__(256) void node_dots_kernel(
    const float* __restrict__ h, const float* __restrict__ W,
    float2* __restrict__ tabA, float2* __restrict__ tabB, int n_nodes) {
  __shared__ float sW[512];  // W [2][256] = 2 KB
  const int tid = threadIdx.x;
  if (tid < 128) {
    reinterpret_cast<float4*>(sW)[tid] = reinterpret_cast<const float4*>(W)[tid];
  }
  __syncthreads();

  const int node = blockIdx.x * 64 + (tid >> 2);
  if (node >= n_nodes) return;
  const int quad = tid & 3;
  const float* hrow = h + (size_t)node * 128;

  float a0 = 0.f, a1 = 0.f, b0 = 0.f, b1 = 0.f;
#pragma unroll
  for (int k = 0; k < 8; ++k) {
    // Disjoint interleaved split (VERIFIED round 1): quad q handles
    // d = 4q + 16k, k=0..7 -> lanes of a quad-group read adjacent 16B
    // chunks (64B contiguous per group per iteration).
    const int d = quad * 4 + k * 16;
    const float4 hv = *reinterpret_cast<const float4*>(hrow + d);
    const float4 w0 = *reinterpret_cast<const float4*>(sW + d);        // W[0][0:128]
    const float4 w1 = *reinterpret_cast<const float4*>(sW + 256 + d);  // W[1][0:128]
    const float4 w2 = *reinterpret_cast<const float4*>(sW + 128 + d);  // W[0][128:]
    const float4 w3 = *reinterpret_cast<const float4*>(sW + 384 + d);  // W[1][128:]
    a0 += hv.x * w0.x + hv.y * w0.y + hv.z * w0.z + hv.w * w0.w;
    a1 += hv.x * w1.x + hv.y * w1.y + hv.z * w1.z + hv.w * w1.w;
    b0 += hv.x * w2.x + hv.y * w2.y + hv.z * w2.z + hv.w * w2.w;
    b1 += hv.x * w3.x + hv.y * w3.y + hv.z * w3.z + hv.w * w3.w;
  }
  // Butterfly across the node's 4 lanes; ALL 4 lanes end with full sums.
  a0 += __shfl_xor(a0, 1); a0 += __shfl_xor(a0, 2);
  a1 += __shfl_xor(a1, 1); a1 += __shfl_xor(a1, 2);
  b0 += __shfl_xor(b0, 1); b0 += __shfl_xor(b0, 2);
  b1 += __shfl_xor(b1, 1); b1 += __shfl_xor(b1, 2);
  if (quad == 0) tabA[node] = make_float2(a0, a1);
  if (quad == 1) tabB[node] = make_float2(b0, b1);
}

__global__ __launch_bounds__(256) void edge_scores_kernel(
    const int* __restrict__ src, const int* __restrict__ dst,
    const float2* __restrict__ tabA, const float2* __restrict__ tabB,
    const float* __restrict__ bias, float2* __restrict__ out, int n_edges) {
  const float bx = bias[0], by = bias[1];
  const int npairs = n_edges >> 1;
  const int p = blockIdx.x * blockDim.x + threadIdx.x;
  if (p < npairs) {
    const int2 s2 = reinterpret_cast<const int2*>(src)[p];
    const int2 d2 = reinterpret_cast<const int2*>(dst)[p];
    const float2 a0 = tabA[s2.x];
    const float2 b0 = tabB[d2.x];
    const float2 a1 = tabA[s2.y];
    const float2 b1 = tabB[d2.y];
    reinterpret_cast<float4*>(out)[p] =
        make_float4(a0.x + b0.x + bx, a0.y + b0.y + by,
                    a1.x + b1.x + bx, a1.y + b1.y + by);
  }
  // odd tail
  if (p == 0 && (n_edges & 1)) {
    const int e = n_edges - 1;
    const float2 a = tabA[src[e]];
    const float2 b = tabB[dst[e]];
    out[e] = make_float2(a.x + b.x + bx, a.y + b.y + by);
  }
}

// Fallback if d_ws is too small: direct per-edge gather + dot.
__global__ __launch_bounds__(256) void edge_direct_kernel(
    const float* __restrict__ h, const int* __restrict__ src,
    const int* __restrict__ dst, const float* __restrict__ W,
    const float* __restrict__ bias, float2* __restrict__ out, int n_edges) {
  __shared__ float sW[512];
  const int tid = threadIdx.x;
  if (tid < 128) {
    reinterpret_cast<float4*>(sW)[tid] = reinterpret_cast<const float4*>(W)[tid];
  }
  __syncthreads();
  const int e = blockIdx.x * blockDim.x + tid;
  if (e >= n_edges) return;
  const float* hu = h + (size_t)src[e] * 128;
  const float* hv = h + (size_t)dst[e] * 128;
  float s0 = bias[0], s1 = bias[1];
#pragma unroll 4
  for (int d = 0; d < 128; d += 4) {
    const float4 u = *reinterpret_cast<const float4*>(hu + d);
    const float4 v = *reinterpret_cast<const float4*>(hv + d);
    const float4 w00 = *reinterpret_cast<const float4*>(sW + d);
    const float4 w01 = *reinterpret_cast<const float4*>(sW + 128 + d);
    const float4 w10 = *reinterpret_cast<const float4*>(sW + 256 + d);
    const float4 w11 = *reinterpret_cast<const float4*>(sW + 384 + d);
    s0 += u.x * w00.x + u.y * w00.y + u.z * w00.z + u.w * w00.w
        + v.x * w01.x + v.y * w01.y + v.z * w01.z + v.w * w01.w;
    s1 += u.x * w10.x + u.y * w10.y + u.z * w10.z + u.w * w10.w
        + v.x * w11.x + v.y * w11.y + v.z * w11.z + v.w * w11.w;
  }
  out[e] = make_float2(s0, s1);
}

extern "C" void kernel_launch(void* const* d_in, const int* in_sizes, int n_in,
                              void* d_out, int out_size, void* d_ws, size_t ws_size,
                              hipStream_t stream) {
  const float* h    = (const float*)d_in[0];
  const int*   src  = (const int*)d_in[1];
  const int*   dst  = (const int*)d_in[2];
  const float* W    = (const float*)d_in[3];
  const float* bias = (const float*)d_in[4];
  float2* out = (float2*)d_out;

  const int n_nodes = in_sizes[0] / 128;
  const int n_edges = in_sizes[1];

  const size_t need = (size_t)n_nodes * 4 * sizeof(float);  // tabA + tabB
  if (ws_size >= need) {
    float2* tabA = (float2*)d_ws;
    float2* tabB = tabA + n_nodes;
    node_dots_kernel<<<(n_nodes + 63) / 64, 256, 0, stream>>>(h, W, tabA, tabB,
                                                              n_nodes);
    const int npairs = (n_edges >> 1) + (n_edges & 1);
    edge_scores_kernel<<<(npairs + 255) / 256, 256, 0, stream>>>(
        src, dst, tabA, tabB, bias, out, n_edges);
  } else {
    edge_direct_kernel<<<(n_edges + 255) / 256, 256, 0, stream>>>(
        h, src, dst, W, bias, out, n_edges);
  }
}